// Round 5
// baseline (235.260 us; speedup 1.0000x reference)
//
#include <hip/hip_runtime.h>
#include <stdint.h>

#define N_V 50000
#define F_DIM 128
#define K_DIM 128
#define H_DIM 3
#define M_DIM 10
#define TILES_PER_BLK 4

using bf16x8 = __attribute__((ext_vector_type(8))) short;  // 8 bf16 = 4 VGPRs
using f32x4  = __attribute__((ext_vector_type(4))) float;
using f32x2  = __attribute__((ext_vector_type(2))) float;
using h4     = __attribute__((ext_vector_type(4))) _Float16;

__device__ inline unsigned short f2bf(float f) {
    union { float f; uint32_t u; } v; v.f = f;
    uint32_t u = v.u;
    u += 0x7fffu + ((u >> 16) & 1u);   // round-to-nearest-even
    return (unsigned short)(u >> 16);
}

__device__ inline uint32_t pkh2(float a, float b) {
    union { _Float16 h[2]; uint32_t u; } v;
    v.h[0] = (_Float16)a; v.h[1] = (_Float16)b;
    return v.u;
}

#define LDS_AS __attribute__((address_space(3)))
__device__ inline void gl2lds16(const void* g, void* l) {
    __builtin_amdgcn_global_load_lds(
        (const __attribute__((address_space(1))) unsigned int*)g,
        (LDS_AS unsigned int*)l, 16, 0, 0);
}

// ---------------------------------------------------------------------------
// Kernel 1 (prep): a) W (H,F,K) fp32 -> Wt[b][k][f] bf16; b) X -> Xb bf16;
// c) wa[b][f] = W_b[f,:] . a_vec_b  -> bf16 (for e = X*wa via MFMA)
// ---------------------------------------------------------------------------
#define WTOT (9 * 128 * 128)
#define XCH  (N_V * 16)
#define WACT (9 * 128)

__global__ void prep(const float* __restrict__ Wvc,
                     const float* __restrict__ Wvn_int,
                     const float* __restrict__ Wvn_nh,
                     const float* __restrict__ X,
                     const float* __restrict__ a,
                     unsigned short* __restrict__ Wt,
                     unsigned short* __restrict__ Xb,
                     unsigned short* __restrict__ wab) {
    int idx = blockIdx.x * 256 + threadIdx.x;
    if (idx < WTOT) {
        int b   = idx >> 14;
        int rem = idx & 16383;
        int k = rem >> 7;
        int f = rem & 127;
        int h = b / 3, t = b - 3 * h;
        const float* src = (t == 0) ? Wvc : (t == 1) ? Wvn_int : Wvn_nh;
        Wt[idx] = f2bf(src[(h * 128 + f) * 128 + k]);
        return;
    }
    int xi = idx - WTOT;
    if (xi < XCH) {
        const float4* Xv = (const float4*)X;
        float4 v0 = Xv[xi * 2];
        float4 v1 = Xv[xi * 2 + 1];
        uint4 o;
        o.x = (uint32_t)f2bf(v0.x) | ((uint32_t)f2bf(v0.y) << 16);
        o.y = (uint32_t)f2bf(v0.z) | ((uint32_t)f2bf(v0.w) << 16);
        o.z = (uint32_t)f2bf(v1.x) | ((uint32_t)f2bf(v1.y) << 16);
        o.w = (uint32_t)f2bf(v1.z) | ((uint32_t)f2bf(v1.w) << 16);
        *(uint4*)&Xb[(size_t)xi * 8] = o;
        return;
    }
    int wi = xi - XCH;
    if (wi < WACT) {
        int b = wi >> 7, f = wi & 127;
        int h = b / 3, t = b - 3 * h;
        const float* src = (t == 0) ? Wvc : (t == 1) ? Wvn_int : Wvn_nh;
        const float4* wrow = (const float4*)&src[(h * 128 + f) * 128];
        const float4* av   = (const float4*)&a[h * 256 + (t == 0 ? 128 : 0)];
        float acc = 0.f;
        #pragma unroll 8
        for (int c = 0; c < 32; ++c) {
            float4 w = wrow[c], x = av[c];
            acc += w.x * x.x + w.y * x.y + w.z * x.z + w.w * x.w;
        }
        wab[b * 128 + f] = f2bf(acc);
    }
}

// ---------------------------------------------------------------------------
// Kernel 2: MFMA GEMM. Grid = (ceil(N/256), 9), 4 waves. Each block owns ONE
// b-matrix (B frags in registers ONCE) and FOUR 64-row M-tiles, pipelined A
// staging. A-fragments loaded per row-tile (afr[4], 16 VGPR) to keep peak
// pressure under the 168-VGPR cap (spill de-risk for do_e blocks).
// Zc stored fp16 (zc16[n][h][128]); V fp8 interleaved [n][h][128] per branch.
// ---------------------------------------------------------------------------
__global__ __launch_bounds__(256, 3) void gemm_kernel(
    const unsigned short* __restrict__ Xb,  // N_V x 128 bf16
    const unsigned short* __restrict__ Wt,  // 9 x 128(k) x 128(f) bf16
    const unsigned short* __restrict__ wab, // 9 x 128 bf16
    _Float16* __restrict__ zc16,            // N_V x 3 x 128 fp16
    uint8_t* __restrict__ Vint,             // N_V x 3 x 128 fp8
    uint8_t* __restrict__ Vnh,              // N_V x 3 x 128 fp8
    float* __restrict__ ec4,                // N_V x 4 (h at component h)
    float* __restrict__ ei4,
    float* __restrict__ en4) {
    __shared__ unsigned short As[2][64 * 128];   // 32 KB double buffer

    const int tid  = threadIdx.x;
    const int b    = blockIdx.y;
    const int hh   = b / 3;
    const int tt   = b - 3 * hh;
    const int wv   = tid >> 6;
    const int lane = tid & 63;
    const int q    = lane >> 4;
    const int ln   = lane & 15;
    const int cb   = (wv >> 1) * 64;   // column half base
    const int rb   = (wv & 1) * 32;    // row half base
    const int m0   = blockIdx.x * (64 * TILES_PER_BLK);

    // ---- stage one 64-row tile into LDS buffer (XOR-16 swizzle) ----------
    auto stage = [&](int buf, int tile) {
        const int mb = m0 + tile * 64;
        #pragma unroll
        for (int it = 0; it < 4; ++it) {
            int c16 = it * 256 + tid;
            int r   = c16 >> 4;
            int p   = c16 & 15;
            int lch = p ^ (r & 15);
            int gr  = mb + r;
            if (gr >= N_V) gr = 0;
            gl2lds16(Xb + (size_t)gr * 128 + lch * 8, &As[buf][c16 * 8]);
        }
    };

    stage(0, 0);

    // ---- B fragments: loaded ONCE, reused for all 4 M-tiles --------------
    const unsigned short* Wb = Wt + (size_t)b * 16384;
    bf16x8 bfr[4][4];
    #pragma unroll
    for (int ct = 0; ct < 4; ++ct) {
        int col = cb + 4 * ln + ct;
        #pragma unroll
        for (int kk = 0; kk < 4; ++kk)
            bfr[ct][kk] = *(const bf16x8*)&Wb[col * 128 + kk * 32 + q * 8];
    }

    // ---- wa columns for e (only y==0 blocks, waves 0,1) ------------------
    const bool do_e = (b == 0) && (wv < 2);
    bf16x8 wz[4];
    if (do_e) {
        #pragma unroll
        for (int kk = 0; kk < 4; ++kk) {
            bf16x8 z = {0, 0, 0, 0, 0, 0, 0, 0};
            if (ln < 9) z = *(const bf16x8*)&wab[ln * 128 + kk * 32 + q * 8];
            wz[kk] = z;
        }
    }

    __syncthreads();   // tile-0 stage + bfr drained

    const int c0 = cb + 4 * ln;
    #pragma unroll
    for (int t = 0; t < TILES_PER_BLK; ++t) {
        const int mb = m0 + t * 64;

        // issue next-tile stage BEFORE compute (overlaps with MFMA below)
        if (t + 1 < TILES_PER_BLK) stage((t + 1) & 1, t + 1);

        f32x4 acc[2][4];
        #pragma unroll
        for (int rt = 0; rt < 2; ++rt)
            #pragma unroll
            for (int ct = 0; ct < 4; ++ct) acc[rt][ct] = (f32x4){0.f, 0.f, 0.f, 0.f};

        #pragma unroll
        for (int rt = 0; rt < 2; ++rt) {
            // A fragments for this row-tile only (16 VGPR live, not 32)
            bf16x8 afr[4];
            const int r = rb + rt * 16 + ln;
            #pragma unroll
            for (int kk = 0; kk < 4; ++kk) {
                int p = (kk * 4 + q) ^ ln;   // unswizzle (r & 15 == ln)
                afr[kk] = *(const bf16x8*)&As[t & 1][r * 128 + p * 8];
            }
            #pragma unroll
            for (int kk = 0; kk < 4; ++kk)
                #pragma unroll
                for (int ct = 0; ct < 4; ++ct)
                    acc[rt][ct] = __builtin_amdgcn_mfma_f32_16x16x32_bf16(
                        afr[kk], bfr[ct][kk], acc[rt][ct], 0, 0, 0);

            // e = A*wa for all 9 b (B cols 0..8 are the wa vectors)
            if (do_e) {
                f32x4 ae = (f32x4){0.f, 0.f, 0.f, 0.f};
                #pragma unroll
                for (int kk = 0; kk < 4; ++kk)
                    ae = __builtin_amdgcn_mfma_f32_16x16x32_bf16(
                        afr[kk], wz[kk], ae, 0, 0, 0);
                if (ln < 9) {
                    int h2 = ln / 3, t2 = ln - 3 * h2;
                    float* ep = (t2 == 0) ? ec4 : (t2 == 1) ? ei4 : en4;
                    #pragma unroll
                    for (int rg = 0; rg < 4; ++rg) {
                        int gr = mb + rb + rt * 16 + q * 4 + rg;
                        if (gr < N_V) ep[gr * 4 + h2] = ae[rg];
                    }
                }
            }
        }

        // barrier: waits for next-tile stage to land; stores go AFTER it so
        // their drain overlaps the next tile's compute.
        __syncthreads();

        if (tt == 0) {
            #pragma unroll
            for (int rt = 0; rt < 2; ++rt)
                #pragma unroll
                for (int rg = 0; rg < 4; ++rg) {
                    int gr = mb + rb + rt * 16 + q * 4 + rg;
                    if (gr >= N_V) continue;
                    uint2 s;
                    s.x = pkh2(acc[rt][0][rg], acc[rt][1][rg]);
                    s.y = pkh2(acc[rt][2][rg], acc[rt][3][rg]);
                    *(uint2*)&zc16[(size_t)gr * 384 + hh * 128 + c0] = s;
                }
        } else {
            uint8_t* Vside = (tt == 1) ? Vint : Vnh;
            #pragma unroll
            for (int rt = 0; rt < 2; ++rt)
                #pragma unroll
                for (int rg = 0; rg < 4; ++rg) {
                    int gr = mb + rb + rt * 16 + q * 4 + rg;
                    if (gr >= N_V) continue;
                    int pk = __builtin_amdgcn_cvt_pk_fp8_f32(
                        acc[rt][0][rg], acc[rt][1][rg], 0, false);
                    pk = __builtin_amdgcn_cvt_pk_fp8_f32(
                        acc[rt][2][rg], acc[rt][3][rg], pk, true);
                    *(uint32_t*)&Vside[((size_t)gr * 3 + hh) * 128 + c0] =
                        (uint32_t)pk;
                }
        }
    }
}

// ---------------------------------------------------------------------------
// Kernel 3: fused attention, all heads. V interleaved [n][h][128]. Zc fp16.
// No max-subtraction. 512-thread blocks (8 vertices), launched as TWO
// half-grid dispatches (visibility diagnostic + lower dispatch pressure).
// ---------------------------------------------------------------------------
__global__ __launch_bounds__(512) void attn_kernel(
    const int* __restrict__ nh_idx, const int* __restrict__ int_idx,
    const float* __restrict__ nh_edge, const float* __restrict__ int_edge,
    const float* __restrict__ bv,        // H x 128
    const uint8_t* __restrict__ Vint,    // N x 3 x 128 fp8
    const uint8_t* __restrict__ Vnh,
    const float* __restrict__ ec4, const float* __restrict__ ei4,
    const float* __restrict__ en4,       // each N x 4
    const _Float16* __restrict__ zc16,   // N x 3 x 128 fp16
    float* __restrict__ out, int n0) {
    const int wv   = threadIdx.x >> 6;
    const int lane = threadIdx.x & 63;
    const int n    = n0 + blockIdx.x * 8 + wv;
    if (n >= N_V) return;
    const int g  = lane >> 4;
    const int gl = lane & 15;

    const bool part = (g <= 1) && (gl < M_DIM);
    int jm = -1; float wm = 0.f;
    if (part) {
        const int*   idx = (g == 0) ? int_idx  : nh_idx;
        const float* ed  = (g == 0) ? int_edge : nh_edge;
        jm = idx[n * M_DIM + gl];
        wm = ed[n * M_DIM + gl];
    }
    const bool  valid = part && (jm >= 0);
    const int   jc    = valid ? jm : 0;
    const float vfl   = valid ? 1.f : 0.f;

    // gather-lane row indices (head-independent): group g handles 5 rows
    const int src_base = (g < 2 ? 0 : 16) + (g & 1) * 5;
    int jrow[5];
    #pragma unroll
    for (int i = 0; i < 5; ++i) jrow[i] = __shfl(jc, src_base + i, 64);

    const uint8_t* Vb = (g < 2) ? Vint : Vnh;
    uint2 pv[3][5];
    #pragma unroll
    for (int i = 0; i < 5; ++i) {
        const uint8_t* base = Vb + (size_t)jrow[i] * 384 + gl * 8;
        #pragma unroll
        for (int h = 0; h < H_DIM; ++h)
            pv[h][i] = *(const uint2*)(base + h * 128);
    }
    float4 ev = make_float4(0.f, 0.f, 0.f, 0.f);
    if (part) ev = *(const float4*)&(((g == 0) ? ei4 : en4)[jc * 4]);
    const float4 ecv = *(const float4*)&ec4[n * 4];

    float4 zc[3], bb[3];
    if (g < 2) {
        #pragma unroll
        for (int h = 0; h < H_DIM; ++h) {
            h4 z = *(const h4*)&zc16[(size_t)n * 384 + h * 128 + gl * 8 + g * 4];
            zc[h] = make_float4((float)z[0], (float)z[1], (float)z[2], (float)z[3]);
            bb[h] = *(const float4*)&bv[h * 128 + gl * 8 + g * 4];
        }
    }

    // valid-count per 16-lane group (head-independent)
    float cf = vfl;
    #pragma unroll
    for (int off = 1; off < 16; off <<= 1) cf += __shfl_xor(cf, off, 64);
    const float cnorm = fmaxf(cf, 1.f);

    #pragma unroll
    for (int h = 0; h < H_DIM; ++h) {
        const float eh  = (h == 0) ? ev.x  : (h == 1) ? ev.y  : ev.z;
        const float ech = (h == 0) ? ecv.x : (h == 1) ? ecv.y : ecv.z;

        // logits bounded (~|4|): no max-subtraction needed
        float l = (part && valid) ? (eh + ech) * wm : 0.f;
        float ex = part ? __expf(l) : 0.f;
        float sv = ex;
        #pragma unroll
        for (int off = 1; off < 16; off <<= 1) sv += __shfl_xor(sv, off, 64);
        float alphap = valid ? ex / (sv * cnorm) : 0.f;

        f32x2 acc2[4];
        #pragma unroll
        for (int c = 0; c < 4; ++c) acc2[c] = (f32x2){0.f, 0.f};
        #pragma unroll
        for (int i = 0; i < 5; ++i) {
            float al = __shfl(alphap, src_base + i, 64);
            f32x2 al2 = (f32x2){al, al};
            uint2 p  = pv[h][i];
            f32x2 f01 = __builtin_amdgcn_cvt_pk_f32_fp8(p.x, false);
            f32x2 f23 = __builtin_amdgcn_cvt_pk_f32_fp8(p.x, true);
            f32x2 f45 = __builtin_amdgcn_cvt_pk_f32_fp8(p.y, false);
            f32x2 f67 = __builtin_amdgcn_cvt_pk_f32_fp8(p.y, true);
            acc2[0] += al2 * f01;
            acc2[1] += al2 * f23;
            acc2[2] += al2 * f45;
            acc2[3] += al2 * f67;
        }
        #pragma unroll
        for (int c = 0; c < 4; ++c) {
            f32x2 v = acc2[c];
            v.x += __shfl_xor(v.x, 16, 64);
            v.y += __shfl_xor(v.y, 16, 64);
            v.x += __shfl_xor(v.x, 32, 64);
            v.y += __shfl_xor(v.y, 32, 64);
            acc2[c] = v;
        }
        if (g < 2) {
            size_t o = (size_t)n * 384 + h * 128 + gl * 8 + g * 4;
            float4 zn;
            if (g == 0) zn = make_float4(acc2[0].x, acc2[0].y, acc2[1].x, acc2[1].y);
            else        zn = make_float4(acc2[2].x, acc2[2].y, acc2[3].x, acc2[3].y);
            float4 r;
            r.x = fmaxf(zc[h].x + zn.x + bb[h].x, 0.f);
            r.y = fmaxf(zc[h].y + zn.y + bb[h].y, 0.f);
            r.z = fmaxf(zc[h].z + zn.z + bb[h].z, 0.f);
            r.w = fmaxf(zc[h].w + zn.w + bb[h].w, 0.f);
            *(float4*)&out[o] = r;
        }
    }
}

// ---------------------------------------------------------------------------
extern "C" void kernel_launch(void* const* d_in, const int* in_sizes, int n_in,
                              void* d_out, int out_size, void* d_ws, size_t ws_size,
                              hipStream_t stream) {
    const float* vertices    = (const float*)d_in[0];
    const int*   nh_indices  = (const int*)d_in[1];
    const int*   int_indices = (const int*)d_in[2];
    const float* nh_edges    = (const float*)d_in[3];
    const float* int_edges   = (const float*)d_in[4];
    // d_in[5] is_int: unused by the reference
    const float* Wvc     = (const float*)d_in[6];
    const float* bv      = (const float*)d_in[7];
    const float* Wvn_int = (const float*)d_in[8];
    const float* Wvn_nh  = (const float*)d_in[9];
    const float* a       = (const float*)d_in[10];
    float* out = (float*)d_out;

    char* ws = (char*)d_ws;
    size_t off = 0;
    unsigned short* Wt = (unsigned short*)(ws + off);
    off += (size_t)WTOT * 2;                  off = (off + 255) & ~(size_t)255;
    unsigned short* wab = (unsigned short*)(ws + off);
    off += (size_t)WACT * 2;                  off = (off + 255) & ~(size_t)255;
    unsigned short* Xb = (unsigned short*)(ws + off);
    off += (size_t)N_V * 128 * 2;             off = (off + 255) & ~(size_t)255;
    uint8_t* Vint = (uint8_t*)(ws + off);
    off += (size_t)H_DIM * N_V * 128;         off = (off + 255) & ~(size_t)255;
    uint8_t* Vnh = (uint8_t*)(ws + off);
    off += (size_t)H_DIM * N_V * 128;         off = (off + 255) & ~(size_t)255;
    _Float16* zc16 = (_Float16*)(ws + off);
    off += (size_t)N_V * 384 * 2;             off = (off + 255) & ~(size_t)255;
    float* ec4 = (float*)(ws + off);
    off += (size_t)N_V * 4 * 4;               off = (off + 255) & ~(size_t)255;
    float* ei4 = (float*)(ws + off);
    off += (size_t)N_V * 4 * 4;               off = (off + 255) & ~(size_t)255;
    float* en4 = (float*)(ws + off);
    off += (size_t)N_V * 4 * 4;

    int prep_threads = WTOT + XCH + WACT;
    prep<<<(prep_threads + 255) / 256, 256, 0, stream>>>(
        Wvc, Wvn_int, Wvn_nh, vertices, a, Wt, Xb, wab);

    dim3 grid_g((N_V + 64 * TILES_PER_BLK - 1) / (64 * TILES_PER_BLK), 9);
    gemm_kernel<<<grid_g, 256, 0, stream>>>(Xb, Wt, wab, zc16, Vint, Vnh,
                                            ec4, ei4, en4);

    attn_kernel<<<3125, 512, 0, stream>>>(
        nh_indices, int_indices, nh_edges, int_edges, bv,
        Vint, Vnh, ec4, ei4, en4, zc16, out, 0);
    attn_kernel<<<3125, 512, 0, stream>>>(
        nh_indices, int_indices, nh_edges, int_edges, bv,
        Vint, Vnh, ec4, ei4, en4, zc16, out, 25000);
}

// Round 6
// 234.575 us; speedup vs baseline: 1.0029x; 1.0029x over previous
//
#include <hip/hip_runtime.h>
#include <hip/hip_bf16.h>
#include <stdint.h>

#define N_V 50000
#define F_DIM 128
#define K_DIM 128
#define H_DIM 3
#define M_DIM 10
#define TILES_PER_BLK 4
#define NBLK 1764        // 196 x-tiles * 9 b-matrices
#define BLK_PER_XCD 221  // ceil(1764/8)
#define NBLK_PAD 1768    // 8 * 221

using bf16x8 = __attribute__((ext_vector_type(8))) short;  // 8 bf16 = 4 VGPRs
using f32x4  = __attribute__((ext_vector_type(4))) float;
using f32x2  = __attribute__((ext_vector_type(2))) float;
using h4     = __attribute__((ext_vector_type(4))) _Float16;

__device__ inline uint32_t pkh2(float a, float b) {
    union { _Float16 h[2]; uint32_t u; } v;
    v.h[0] = (_Float16)a; v.h[1] = (_Float16)b;
    return v.u;
}

// pack 2 floats -> 2 bf16 (RNE, bit-identical to the old f2bf path)
__device__ inline uint32_t pkbf2(float a, float b) {
    __hip_bfloat162 p = __float22bfloat162_rn(make_float2(a, b));
    union { __hip_bfloat162 h; uint32_t u; } v; v.h = p;
    return v.u;
}

// ---------------------------------------------------------------------------
// Fused GEMM (absorbs all prep): grid 1D NBLK_PAD, XCD-chunked decode so the
// 9 b-slices of one x-tile run consecutively on one XCD (X fp32 L2-hot).
// Per block: one b-matrix, four 64-row M-tiles.
//  - B frags: scattered fp32 W loads + cvt, once per block (L2-resident).
//  - A tiles: reg-staged X fp32 -> cvt_pk bf16 -> XOR-16 swizzled LDS.
//  - e = sum_col Z[n][col]*a[col] computed from the accumulator in fp32
//    (per-thread ct-dot, 16-lane shfl reduce, LDS atomicAdd) in EVERY block.
// Outputs: zc16 fp16 [n][h][128], V fp8 [n][h][128] per branch, e arrays.
// ---------------------------------------------------------------------------
__global__ __launch_bounds__(256, 3) void gemm_kernel(
    const float* __restrict__ X,        // N_V x 128 fp32
    const float* __restrict__ Wvc,
    const float* __restrict__ Wvn_int,
    const float* __restrict__ Wvn_nh,
    const float* __restrict__ a,        // H x 256
    _Float16* __restrict__ zc16,        // N_V x 3 x 128 fp16
    uint8_t* __restrict__ Vint,         // N_V x 3 x 128 fp8
    uint8_t* __restrict__ Vnh,          // N_V x 3 x 128 fp8
    float* __restrict__ ec4,            // N_V x 4 (h at component h)
    float* __restrict__ ei4,
    float* __restrict__ en4) {
    __shared__ unsigned short As[2][64 * 128];       // 32 KB double buffer
    __shared__ float e_part[TILES_PER_BLK][64];      // 1 KB

    // ---- XCD-chunked decode -------------------------------------------------
    const int c = blockIdx.x & 7;
    const int s = blockIdx.x >> 3;
    const int g = c * BLK_PER_XCD + s;
    if (g >= NBLK) return;
    const int x  = g / 9;
    const int b  = g - 9 * x;
    const int hh = b / 3;
    const int tt = b - 3 * hh;

    const int tid  = threadIdx.x;
    const int wv   = tid >> 6;
    const int lane = tid & 63;
    const int q    = lane >> 4;
    const int ln   = lane & 15;
    const int cb   = (wv >> 1) * 64;   // column half base
    const int rb   = (wv & 1) * 32;    // row half base
    const int m0   = x * (64 * TILES_PER_BLK);

    const float* Wb = ((tt == 0) ? Wvc : (tt == 1) ? Wvn_int : Wvn_nh)
                      + (size_t)hh * 16384;   // [f][k] 128x128 fp32

    // ---- stage one 64-row X tile: fp32 global -> bf16 swizzled LDS ----------
    auto stage = [&](int buf, int tile) {
        const int mb = m0 + tile * 64;
        float4 xa[4], xb[4];
        int lc[4];
        #pragma unroll
        for (int it = 0; it < 4; ++it) {
            int ch = it * 256 + tid;
            int r  = ch >> 4;
            int pg = ch & 15;
            int gr = mb + r;
            if (gr >= N_V) gr = 0;
            const float4* src = (const float4*)(X + (size_t)gr * 128 + pg * 8);
            xa[it] = src[0];
            xb[it] = src[1];
            lc[it] = (r * 16 + (pg ^ (r & 15))) * 8;   // XOR-16 swizzle
        }
        #pragma unroll
        for (int it = 0; it < 4; ++it) {
            uint4 o;
            o.x = pkbf2(xa[it].x, xa[it].y);
            o.y = pkbf2(xa[it].z, xa[it].w);
            o.z = pkbf2(xb[it].x, xb[it].y);
            o.w = pkbf2(xb[it].z, xb[it].w);
            *(uint4*)&As[buf][lc[it]] = o;
        }
    };

    stage(0, 0);

    // ---- B fragments from fp32 W (scattered, once per block, L2-hot) -------
    bf16x8 bfr[4][4];
    #pragma unroll
    for (int ct = 0; ct < 4; ++ct) {
        const int col = cb + 4 * ln + ct;
        #pragma unroll
        for (int kk = 0; kk < 4; ++kk) {
            const float* wp = Wb + (size_t)(kk * 32 + q * 8) * 128 + col;
            float v0 = wp[0 * 128], v1 = wp[1 * 128], v2 = wp[2 * 128], v3 = wp[3 * 128];
            float v4 = wp[4 * 128], v5 = wp[5 * 128], v6 = wp[6 * 128], v7 = wp[7 * 128];
            union { uint32_t u[4]; bf16x8 v; } pk;
            pk.u[0] = pkbf2(v0, v1);
            pk.u[1] = pkbf2(v2, v3);
            pk.u[2] = pkbf2(v4, v5);
            pk.u[3] = pkbf2(v6, v7);
            bfr[ct][kk] = pk.v;
        }
    }

    // ---- a-coefficients for this thread's 4 output columns ------------------
    const float* av = a + hh * 256 + (tt == 0 ? 128 : 0);
    float acoef[4];
    #pragma unroll
    for (int ct = 0; ct < 4; ++ct) acoef[ct] = av[cb + 4 * ln + ct];

    // zero e accumulators
    if (tid < 64) {
        #pragma unroll
        for (int t = 0; t < TILES_PER_BLK; ++t) e_part[t][tid] = 0.f;
    }

    __syncthreads();   // tile-0 stage visible

    const int c0 = cb + 4 * ln;
    #pragma unroll
    for (int t = 0; t < TILES_PER_BLK; ++t) {
        const int mb = m0 + t * 64;

        // fully stage next tile (regs released before MFMA; other waves hide it)
        if (t + 1 < TILES_PER_BLK) stage((t + 1) & 1, t + 1);

        f32x4 acc[2][4];
        #pragma unroll
        for (int rt = 0; rt < 2; ++rt)
            #pragma unroll
            for (int ct = 0; ct < 4; ++ct) acc[rt][ct] = (f32x4){0.f, 0.f, 0.f, 0.f};

        #pragma unroll
        for (int rt = 0; rt < 2; ++rt) {
            bf16x8 afr[4];
            const int r = rb + rt * 16 + ln;
            #pragma unroll
            for (int kk = 0; kk < 4; ++kk) {
                int p = (kk * 4 + q) ^ ln;   // unswizzle (r & 15 == ln)
                afr[kk] = *(const bf16x8*)&As[t & 1][r * 128 + p * 8];
            }
            #pragma unroll
            for (int kk = 0; kk < 4; ++kk)
                #pragma unroll
                for (int ct = 0; ct < 4; ++ct)
                    acc[rt][ct] = __builtin_amdgcn_mfma_f32_16x16x32_bf16(
                        afr[kk], bfr[ct][kk], acc[rt][ct], 0, 0, 0);
        }

        // ---- e = Z . a  (fp32 epilogue, every block) ------------------------
        #pragma unroll
        for (int rt = 0; rt < 2; ++rt) {
            #pragma unroll
            for (int rg = 0; rg < 4; ++rg) {
                float p = acc[rt][0][rg] * acoef[0] + acc[rt][1][rg] * acoef[1]
                        + acc[rt][2][rg] * acoef[2] + acc[rt][3][rg] * acoef[3];
                #pragma unroll
                for (int off = 1; off < 16; off <<= 1)
                    p += __shfl_xor(p, off, 64);
                if (ln == 0)
                    atomicAdd(&e_part[t][rb + rt * 16 + q * 4 + rg], p);
            }
        }

        __syncthreads();   // staged tile + e atomics visible

        if (tt == 0) {
            #pragma unroll
            for (int rt = 0; rt < 2; ++rt)
                #pragma unroll
                for (int rg = 0; rg < 4; ++rg) {
                    int gr = mb + rb + rt * 16 + q * 4 + rg;
                    if (gr >= N_V) continue;
                    uint2 sv;
                    sv.x = pkh2(acc[rt][0][rg], acc[rt][1][rg]);
                    sv.y = pkh2(acc[rt][2][rg], acc[rt][3][rg]);
                    *(uint2*)&zc16[(size_t)gr * 384 + hh * 128 + c0] = sv;
                }
        } else {
            uint8_t* Vside = (tt == 1) ? Vint : Vnh;
            #pragma unroll
            for (int rt = 0; rt < 2; ++rt)
                #pragma unroll
                for (int rg = 0; rg < 4; ++rg) {
                    int gr = mb + rb + rt * 16 + q * 4 + rg;
                    if (gr >= N_V) continue;
                    int pk = __builtin_amdgcn_cvt_pk_fp8_f32(
                        acc[rt][0][rg], acc[rt][1][rg], 0, false);
                    pk = __builtin_amdgcn_cvt_pk_fp8_f32(
                        acc[rt][2][rg], acc[rt][3][rg], pk, true);
                    *(uint32_t*)&Vside[((size_t)gr * 3 + hh) * 128 + c0] =
                        (uint32_t)pk;
                }
        }
    }

    // ---- write e for this block's 256 rows ----------------------------------
    {
        int ti = tid >> 6, r = tid & 63;
        int gr = m0 + ti * 64 + r;
        if (gr < N_V) {
            float* ep = (tt == 0) ? ec4 : (tt == 1) ? ei4 : en4;
            ep[gr * 4 + hh] = e_part[ti][r];
        }
    }
}

// ---------------------------------------------------------------------------
// Fused attention, all heads, single dispatch. V interleaved [n][h][128],
// Zc fp16, no max-subtraction (logits bounded), f32x2 pk-fma accumulation.
// ---------------------------------------------------------------------------
__global__ __launch_bounds__(256) void attn_kernel(
    const int* __restrict__ nh_idx, const int* __restrict__ int_idx,
    const float* __restrict__ nh_edge, const float* __restrict__ int_edge,
    const float* __restrict__ bv,        // H x 128
    const uint8_t* __restrict__ Vint,    // N x 3 x 128 fp8
    const uint8_t* __restrict__ Vnh,
    const float* __restrict__ ec4, const float* __restrict__ ei4,
    const float* __restrict__ en4,       // each N x 4
    const _Float16* __restrict__ zc16,   // N x 3 x 128 fp16
    float* __restrict__ out) {
    const int wv   = threadIdx.x >> 6;
    const int lane = threadIdx.x & 63;
    const int n    = blockIdx.x * 4 + wv;
    if (n >= N_V) return;
    const int g  = lane >> 4;
    const int gl = lane & 15;

    const bool part = (g <= 1) && (gl < M_DIM);
    int jm = -1; float wm = 0.f;
    if (part) {
        const int*   idx = (g == 0) ? int_idx  : nh_idx;
        const float* ed  = (g == 0) ? int_edge : nh_edge;
        jm = idx[n * M_DIM + gl];
        wm = ed[n * M_DIM + gl];
    }
    const bool  valid = part && (jm >= 0);
    const int   jc    = valid ? jm : 0;
    const float vfl   = valid ? 1.f : 0.f;

    // gather-lane row indices (head-independent): group g handles 5 rows
    const int src_base = (g < 2 ? 0 : 16) + (g & 1) * 5;
    int jrow[5];
    #pragma unroll
    for (int i = 0; i < 5; ++i) jrow[i] = __shfl(jc, src_base + i, 64);

    const uint8_t* Vb = (g < 2) ? Vint : Vnh;
    uint2 pv[3][5];
    #pragma unroll
    for (int i = 0; i < 5; ++i) {
        const uint8_t* base = Vb + (size_t)jrow[i] * 384 + gl * 8;
        #pragma unroll
        for (int h = 0; h < H_DIM; ++h)
            pv[h][i] = *(const uint2*)(base + h * 128);
    }
    float4 ev = make_float4(0.f, 0.f, 0.f, 0.f);
    if (part) ev = *(const float4*)&(((g == 0) ? ei4 : en4)[jc * 4]);
    const float4 ecv = *(const float4*)&ec4[n * 4];

    float4 zc[3], bb[3];
    if (g < 2) {
        #pragma unroll
        for (int h = 0; h < H_DIM; ++h) {
            h4 z = *(const h4*)&zc16[(size_t)n * 384 + h * 128 + gl * 8 + g * 4];
            zc[h] = make_float4((float)z[0], (float)z[1], (float)z[2], (float)z[3]);
            bb[h] = *(const float4*)&bv[h * 128 + gl * 8 + g * 4];
        }
    }

    // valid-count per 16-lane group (head-independent)
    float cf = vfl;
    #pragma unroll
    for (int off = 1; off < 16; off <<= 1) cf += __shfl_xor(cf, off, 64);
    const float cnorm = fmaxf(cf, 1.f);

    #pragma unroll
    for (int h = 0; h < H_DIM; ++h) {
        const float eh  = (h == 0) ? ev.x  : (h == 1) ? ev.y  : ev.z;
        const float ech = (h == 0) ? ecv.x : (h == 1) ? ecv.y : ecv.z;

        // logits bounded (~|4|): no max-subtraction needed
        float l = (part && valid) ? (eh + ech) * wm : 0.f;
        float ex = part ? __expf(l) : 0.f;
        float sv = ex;
        #pragma unroll
        for (int off = 1; off < 16; off <<= 1) sv += __shfl_xor(sv, off, 64);
        float alphap = valid ? ex / (sv * cnorm) : 0.f;

        f32x2 acc2[4];
        #pragma unroll
        for (int c = 0; c < 4; ++c) acc2[c] = (f32x2){0.f, 0.f};
        #pragma unroll
        for (int i = 0; i < 5; ++i) {
            float al = __shfl(alphap, src_base + i, 64);
            f32x2 al2 = (f32x2){al, al};
            uint2 p  = pv[h][i];
            f32x2 f01 = __builtin_amdgcn_cvt_pk_f32_fp8(p.x, false);
            f32x2 f23 = __builtin_amdgcn_cvt_pk_f32_fp8(p.x, true);
            f32x2 f45 = __builtin_amdgcn_cvt_pk_f32_fp8(p.y, false);
            f32x2 f67 = __builtin_amdgcn_cvt_pk_f32_fp8(p.y, true);
            acc2[0] += al2 * f01;
            acc2[1] += al2 * f23;
            acc2[2] += al2 * f45;
            acc2[3] += al2 * f67;
        }
        #pragma unroll
        for (int c = 0; c < 4; ++c) {
            f32x2 v = acc2[c];
            v.x += __shfl_xor(v.x, 16, 64);
            v.y += __shfl_xor(v.y, 16, 64);
            v.x += __shfl_xor(v.x, 32, 64);
            v.y += __shfl_xor(v.y, 32, 64);
            acc2[c] = v;
        }
        if (g < 2) {
            size_t o = (size_t)n * 384 + h * 128 + gl * 8 + g * 4;
            float4 zn;
            if (g == 0) zn = make_float4(acc2[0].x, acc2[0].y, acc2[1].x, acc2[1].y);
            else        zn = make_float4(acc2[2].x, acc2[2].y, acc2[3].x, acc2[3].y);
            float4 r;
            r.x = fmaxf(zc[h].x + zn.x + bb[h].x, 0.f);
            r.y = fmaxf(zc[h].y + zn.y + bb[h].y, 0.f);
            r.z = fmaxf(zc[h].z + zn.z + bb[h].z, 0.f);
            r.w = fmaxf(zc[h].w + zn.w + bb[h].w, 0.f);
            *(float4*)&out[o] = r;
        }
    }
}

// ---------------------------------------------------------------------------
extern "C" void kernel_launch(void* const* d_in, const int* in_sizes, int n_in,
                              void* d_out, int out_size, void* d_ws, size_t ws_size,
                              hipStream_t stream) {
    const float* vertices    = (const float*)d_in[0];
    const int*   nh_indices  = (const int*)d_in[1];
    const int*   int_indices = (const int*)d_in[2];
    const float* nh_edges    = (const float*)d_in[3];
    const float* int_edges   = (const float*)d_in[4];
    // d_in[5] is_int: unused by the reference
    const float* Wvc     = (const float*)d_in[6];
    const float* bv      = (const float*)d_in[7];
    const float* Wvn_int = (const float*)d_in[8];
    const float* Wvn_nh  = (const float*)d_in[9];
    const float* a       = (const float*)d_in[10];
    float* out = (float*)d_out;

    char* ws = (char*)d_ws;
    size_t off = 0;
    uint8_t* Vint = (uint8_t*)(ws + off);
    off += (size_t)H_DIM * N_V * 128;         off = (off + 255) & ~(size_t)255;
    uint8_t* Vnh = (uint8_t*)(ws + off);
    off += (size_t)H_DIM * N_V * 128;         off = (off + 255) & ~(size_t)255;
    _Float16* zc16 = (_Float16*)(ws + off);
    off += (size_t)N_V * 384 * 2;             off = (off + 255) & ~(size_t)255;
    float* ec4 = (float*)(ws + off);
    off += (size_t)N_V * 4 * 4;               off = (off + 255) & ~(size_t)255;
    float* ei4 = (float*)(ws + off);
    off += (size_t)N_V * 4 * 4;               off = (off + 255) & ~(size_t)255;
    float* en4 = (float*)(ws + off);
    off += (size_t)N_V * 4 * 4;

    gemm_kernel<<<NBLK_PAD, 256, 0, stream>>>(
        vertices, Wvc, Wvn_int, Wvn_nh, a,
        zc16, Vint, Vnh, ec4, ei4, en4);

    attn_kernel<<<(N_V + 3) / 4, 256, 0, stream>>>(
        nh_indices, int_indices, nh_edges, int_edges, bv,
        Vint, Vnh, ec4, ei4, en4, zc16, out);
}

// Round 7
// 221.982 us; speedup vs baseline: 1.0598x; 1.0567x over previous
//
#include <hip/hip_runtime.h>
#include <stdint.h>

#define N_V 50000
#define F_DIM 128
#define K_DIM 128
#define H_DIM 3
#define M_DIM 10
#define TILES_PER_BLK 4
#define NBLK 1764        // 196 x-tiles * 9 b-matrices
#define BLK_PER_XCD 221  // ceil(1764/8)
#define NBLK_PAD 1768    // 8 * 221

using bf16x8 = __attribute__((ext_vector_type(8))) short;  // 8 bf16 = 4 VGPRs
using f32x4  = __attribute__((ext_vector_type(4))) float;
using f32x2  = __attribute__((ext_vector_type(2))) float;
using h4     = __attribute__((ext_vector_type(4))) _Float16;

__device__ inline unsigned short f2bf(float f) {
    union { float f; uint32_t u; } v; v.f = f;
    uint32_t u = v.u;
    u += 0x7fffu + ((u >> 16) & 1u);   // round-to-nearest-even
    return (unsigned short)(u >> 16);
}

__device__ inline uint32_t pkh2(float a, float b) {
    union { _Float16 h[2]; uint32_t u; } v;
    v.h[0] = (_Float16)a; v.h[1] = (_Float16)b;
    return v.u;
}

#define LDS_AS __attribute__((address_space(3)))
__device__ inline void gl2lds16(const void* g, void* l) {
    __builtin_amdgcn_global_load_lds(
        (const __attribute__((address_space(1))) unsigned int*)g,
        (LDS_AS unsigned int*)l, 16, 0, 0);
}

// ---------------------------------------------------------------------------
// Kernel 1 (prep): a) W (H,F,K) fp32 -> Wt[b][k][f] bf16; b) X -> Xb bf16;
// c) wa[b][f] = W_b[f,:] . a_vec_b  -> bf16 (for e = X*wa via MFMA)
// ---------------------------------------------------------------------------
#define WTOT (9 * 128 * 128)
#define XCH  (N_V * 16)
#define WACT (9 * 128)

__global__ void prep(const float* __restrict__ Wvc,
                     const float* __restrict__ Wvn_int,
                     const float* __restrict__ Wvn_nh,
                     const float* __restrict__ X,
                     const float* __restrict__ a,
                     unsigned short* __restrict__ Wt,
                     unsigned short* __restrict__ Xb,
                     unsigned short* __restrict__ wab) {
    int idx = blockIdx.x * 256 + threadIdx.x;
    if (idx < WTOT) {
        int b   = idx >> 14;
        int rem = idx & 16383;
        int k = rem >> 7;
        int f = rem & 127;
        int h = b / 3, t = b - 3 * h;
        const float* src = (t == 0) ? Wvc : (t == 1) ? Wvn_int : Wvn_nh;
        Wt[idx] = f2bf(src[(h * 128 + f) * 128 + k]);
        return;
    }
    int xi = idx - WTOT;
    if (xi < XCH) {
        const float4* Xv = (const float4*)X;
        float4 v0 = Xv[xi * 2];
        float4 v1 = Xv[xi * 2 + 1];
        uint4 o;
        o.x = (uint32_t)f2bf(v0.x) | ((uint32_t)f2bf(v0.y) << 16);
        o.y = (uint32_t)f2bf(v0.z) | ((uint32_t)f2bf(v0.w) << 16);
        o.z = (uint32_t)f2bf(v1.x) | ((uint32_t)f2bf(v1.y) << 16);
        o.w = (uint32_t)f2bf(v1.z) | ((uint32_t)f2bf(v1.w) << 16);
        *(uint4*)&Xb[(size_t)xi * 8] = o;
        return;
    }
    int wi = xi - XCH;
    if (wi < WACT) {
        int b = wi >> 7, f = wi & 127;
        int h = b / 3, t = b - 3 * h;
        const float* src = (t == 0) ? Wvc : (t == 1) ? Wvn_int : Wvn_nh;
        const float4* wrow = (const float4*)&src[(h * 128 + f) * 128];
        const float4* av   = (const float4*)&a[h * 256 + (t == 0 ? 128 : 0)];
        float acc = 0.f;
        #pragma unroll 8
        for (int c = 0; c < 32; ++c) {
            float4 w = wrow[c], x = av[c];
            acc += w.x * x.x + w.y * x.y + w.z * x.z + w.w * x.w;
        }
        wab[b * 128 + f] = f2bf(acc);
    }
}

// ---------------------------------------------------------------------------
// Kernel 2: MFMA GEMM (R5 structure + XCD-chunked 1D grid). Each block owns
// ONE b-matrix (B frags from coalesced Wt, loaded once) and FOUR 64-row
// M-tiles with pipelined A staging. The 9 b-slices of one x-tile run
// consecutively on ONE XCD -> Xb reads L2-hot. Zc written as fp16 halves
// INTO the fp32 out buffer (first 384 of 768 half-slots per row).
// ---------------------------------------------------------------------------
__global__ __launch_bounds__(256, 3) void gemm_kernel(
    const unsigned short* __restrict__ Xb,  // N_V x 128 bf16
    const unsigned short* __restrict__ Wt,  // 9 x 128(k) x 128(f) bf16
    const unsigned short* __restrict__ wab, // 9 x 128 bf16
    _Float16* __restrict__ zc16,            // = (half*)out: n*768 + h*128 + c
    uint8_t* __restrict__ Vint,             // N_V x 3 x 128 fp8
    uint8_t* __restrict__ Vnh,              // N_V x 3 x 128 fp8
    float* __restrict__ ec4,                // N_V x 4 (h at component h)
    float* __restrict__ ei4,
    float* __restrict__ en4) {
    __shared__ unsigned short As[2][64 * 128];   // 32 KB double buffer

    // ---- XCD-chunked decode ----------------------------------------------
    const int xc = blockIdx.x & 7;
    const int sq = blockIdx.x >> 3;
    const int gB = xc * BLK_PER_XCD + sq;
    if (gB >= NBLK) return;
    const int x  = gB / 9;
    const int b  = gB - 9 * x;
    const int hh = b / 3;
    const int tt = b - 3 * hh;

    const int tid  = threadIdx.x;
    const int wv   = tid >> 6;
    const int lane = tid & 63;
    const int q    = lane >> 4;
    const int ln   = lane & 15;
    const int cb   = (wv >> 1) * 64;   // column half base
    const int rb   = (wv & 1) * 32;    // row half base
    const int m0   = x * (64 * TILES_PER_BLK);

    // ---- stage one 64-row tile into LDS buffer (XOR-16 swizzle) ----------
    auto stage = [&](int buf, int tile) {
        const int mb = m0 + tile * 64;
        #pragma unroll
        for (int it = 0; it < 4; ++it) {
            int c16 = it * 256 + tid;
            int r   = c16 >> 4;
            int p   = c16 & 15;
            int lch = p ^ (r & 15);
            int gr  = mb + r;
            if (gr >= N_V) gr = 0;
            gl2lds16(Xb + (size_t)gr * 128 + lch * 8, &As[buf][c16 * 8]);
        }
    };

    stage(0, 0);

    // ---- B fragments: loaded ONCE, reused for all 4 M-tiles --------------
    const unsigned short* Wb = Wt + (size_t)b * 16384;
    bf16x8 bfr[4][4];
    #pragma unroll
    for (int ct = 0; ct < 4; ++ct) {
        int col = cb + 4 * ln + ct;
        #pragma unroll
        for (int kk = 0; kk < 4; ++kk)
            bfr[ct][kk] = *(const bf16x8*)&Wb[col * 128 + kk * 32 + q * 8];
    }

    // ---- wa columns for e (only b==0 blocks, waves 0,1) ------------------
    const bool do_e = (b == 0) && (wv < 2);
    bf16x8 wz[4];
    if (do_e) {
        #pragma unroll
        for (int kk = 0; kk < 4; ++kk) {
            bf16x8 z = {0, 0, 0, 0, 0, 0, 0, 0};
            if (ln < 9) z = *(const bf16x8*)&wab[ln * 128 + kk * 32 + q * 8];
            wz[kk] = z;
        }
    }

    __syncthreads();   // tile-0 stage + bfr drained

    const int c0 = cb + 4 * ln;
    #pragma unroll
    for (int t = 0; t < TILES_PER_BLK; ++t) {
        const int mb = m0 + t * 64;

        // issue next-tile stage BEFORE compute (overlaps with MFMA below)
        if (t + 1 < TILES_PER_BLK) stage((t + 1) & 1, t + 1);

        f32x4 acc[2][4];
        #pragma unroll
        for (int rt = 0; rt < 2; ++rt)
            #pragma unroll
            for (int ct = 0; ct < 4; ++ct) acc[rt][ct] = (f32x4){0.f, 0.f, 0.f, 0.f};

        #pragma unroll
        for (int rt = 0; rt < 2; ++rt) {
            // A fragments for this row-tile only (16 VGPR live, not 32)
            bf16x8 afr[4];
            const int r = rb + rt * 16 + ln;
            #pragma unroll
            for (int kk = 0; kk < 4; ++kk) {
                int p = (kk * 4 + q) ^ ln;   // unswizzle (r & 15 == ln)
                afr[kk] = *(const bf16x8*)&As[t & 1][r * 128 + p * 8];
            }
            #pragma unroll
            for (int kk = 0; kk < 4; ++kk)
                #pragma unroll
                for (int ct = 0; ct < 4; ++ct)
                    acc[rt][ct] = __builtin_amdgcn_mfma_f32_16x16x32_bf16(
                        afr[kk], bfr[ct][kk], acc[rt][ct], 0, 0, 0);

            // e = A*wa for all 9 b (B cols 0..8 are the wa vectors)
            if (do_e) {
                f32x4 ae = (f32x4){0.f, 0.f, 0.f, 0.f};
                #pragma unroll
                for (int kk = 0; kk < 4; ++kk)
                    ae = __builtin_amdgcn_mfma_f32_16x16x32_bf16(
                        afr[kk], wz[kk], ae, 0, 0, 0);
                if (ln < 9) {
                    int h2 = ln / 3, t2 = ln - 3 * h2;
                    float* ep = (t2 == 0) ? ec4 : (t2 == 1) ? ei4 : en4;
                    #pragma unroll
                    for (int rg = 0; rg < 4; ++rg) {
                        int gr = mb + rb + rt * 16 + q * 4 + rg;
                        if (gr < N_V) ep[gr * 4 + h2] = ae[rg];
                    }
                }
            }
        }

        // barrier: waits for next-tile stage to land; stores go AFTER it so
        // their drain overlaps the next tile's compute.
        __syncthreads();

        if (tt == 0) {
            #pragma unroll
            for (int rt = 0; rt < 2; ++rt)
                #pragma unroll
                for (int rg = 0; rg < 4; ++rg) {
                    int gr = mb + rb + rt * 16 + q * 4 + rg;
                    if (gr >= N_V) continue;
                    uint2 s;
                    s.x = pkh2(acc[rt][0][rg], acc[rt][1][rg]);
                    s.y = pkh2(acc[rt][2][rg], acc[rt][3][rg]);
                    *(uint2*)&zc16[(size_t)gr * 768 + hh * 128 + c0] = s;
                }
        } else {
            uint8_t* Vside = (tt == 1) ? Vint : Vnh;
            #pragma unroll
            for (int rt = 0; rt < 2; ++rt)
                #pragma unroll
                for (int rg = 0; rg < 4; ++rg) {
                    int gr = mb + rb + rt * 16 + q * 4 + rg;
                    if (gr >= N_V) continue;
                    int pk = __builtin_amdgcn_cvt_pk_fp8_f32(
                        acc[rt][0][rg], acc[rt][1][rg], 0, false);
                    pk = __builtin_amdgcn_cvt_pk_fp8_f32(
                        acc[rt][2][rg], acc[rt][3][rg], pk, true);
                    *(uint32_t*)&Vside[((size_t)gr * 3 + hh) * 128 + c0] =
                        (uint32_t)pk;
                }
        }
    }
}

// ---------------------------------------------------------------------------
// Kernel 3: fused attention, all heads. V interleaved [n][h][128], Zc fp16
// read from the out buffer (first 384 half-slots/row), no max-subtraction.
// Load cluster PINNED live via asm uses (defeats IR-level load sinking) so
// all 30 gather dwords + e/zc/bias are in flight together.
// ---------------------------------------------------------------------------
__global__ __launch_bounds__(256, 4) void attn_kernel(
    const int* __restrict__ nh_idx, const int* __restrict__ int_idx,
    const float* __restrict__ nh_edge, const float* __restrict__ int_edge,
    const float* __restrict__ bv,        // H x 128
    const uint8_t* __restrict__ Vint,    // N x 3 x 128 fp8
    const uint8_t* __restrict__ Vnh,
    const float* __restrict__ ec4, const float* __restrict__ ei4,
    const float* __restrict__ en4,       // each N x 4
    float* __restrict__ out) {
    const _Float16* zcp = (const _Float16*)out;   // zc at n*768 + h*128 + c
    const int wv   = threadIdx.x >> 6;
    const int lane = threadIdx.x & 63;
    const int n    = blockIdx.x * 4 + wv;
    if (n >= N_V) return;
    const int g  = lane >> 4;
    const int gl = lane & 15;
    const int gg = g & 1;

    const bool part = (g <= 1) && (gl < M_DIM);
    int jm = -1; float wm = 0.f;
    if (part) {
        const int*   idx = (g == 0) ? int_idx  : nh_idx;
        const float* ed  = (g == 0) ? int_edge : nh_edge;
        jm = idx[n * M_DIM + gl];
        wm = ed[n * M_DIM + gl];
    }
    const bool  valid = part && (jm >= 0);
    const int   jc    = valid ? jm : 0;
    const float vfl   = valid ? 1.f : 0.f;

    // gather-lane row indices (head-independent): group g handles 5 rows
    const int src_base = (g < 2 ? 0 : 16) + (g & 1) * 5;
    int jrow[5];
    #pragma unroll
    for (int i = 0; i < 5; ++i) jrow[i] = __shfl(jc, src_base + i, 64);

    // ---- LOAD CLUSTER ----------------------------------------------------
    const uint8_t* Vb = (g < 2) ? Vint : Vnh;
    uint2 pv[3][5];
    #pragma unroll
    for (int i = 0; i < 5; ++i) {
        const uint8_t* base = Vb + (size_t)jrow[i] * 384 + gl * 8;
        #pragma unroll
        for (int h = 0; h < H_DIM; ++h)
            pv[h][i] = *(const uint2*)(base + h * 128);
    }
    float4 ev = make_float4(0.f, 0.f, 0.f, 0.f);
    if (part) ev = *(const float4*)&(((g == 0) ? ei4 : en4)[jc * 4]);
    const float4 ecv = *(const float4*)&ec4[n * 4];

    float4 zc[3], bb[3];
    #pragma unroll
    for (int h = 0; h < H_DIM; ++h) {
        h4 z = *(const h4*)&zcp[(size_t)n * 768 + h * 128 + gl * 8 + gg * 4];
        zc[h] = make_float4((float)z[0], (float)z[1], (float)z[2], (float)z[3]);
        bb[h] = *(const float4*)&bv[h * 128 + gl * 8 + gg * 4];
    }

    // valid-count reduce (ds ops) co-scheduled under the load latency
    float cf = vfl;
    #pragma unroll
    for (int off = 1; off < 16; off <<= 1) cf += __shfl_xor(cf, off, 64);
    const float cnorm = fmaxf(cf, 1.f);

    // ---- PIN: asm uses make every loaded value live here (no sinking) ----
    #pragma unroll
    for (int h = 0; h < H_DIM; ++h)
        #pragma unroll
        for (int i = 0; i < 5; ++i)
            asm volatile("" :: "v"(pv[h][i].x), "v"(pv[h][i].y));
    asm volatile("" :: "v"(ev.x), "v"(ev.y), "v"(ev.z));
    asm volatile("" :: "v"(ecv.x), "v"(ecv.y), "v"(ecv.z));
    #pragma unroll
    for (int h = 0; h < H_DIM; ++h) {
        asm volatile("" :: "v"(zc[h].x), "v"(zc[h].y), "v"(zc[h].z), "v"(zc[h].w));
        asm volatile("" :: "v"(bb[h].x), "v"(bb[h].y), "v"(bb[h].z), "v"(bb[h].w));
    }

    #pragma unroll
    for (int h = 0; h < H_DIM; ++h) {
        const float eh  = (h == 0) ? ev.x  : (h == 1) ? ev.y  : ev.z;
        const float ech = (h == 0) ? ecv.x : (h == 1) ? ecv.y : ecv.z;

        // logits bounded (~|4|): no max-subtraction needed
        float l = (part && valid) ? (eh + ech) * wm : 0.f;
        float ex = part ? __expf(l) : 0.f;
        float sv = ex;
        #pragma unroll
        for (int off = 1; off < 16; off <<= 1) sv += __shfl_xor(sv, off, 64);
        float alphap = valid ? ex / (sv * cnorm) : 0.f;

        f32x2 acc2[4];
        #pragma unroll
        for (int c = 0; c < 4; ++c) acc2[c] = (f32x2){0.f, 0.f};
        #pragma unroll
        for (int i = 0; i < 5; ++i) {
            float al = __shfl(alphap, src_base + i, 64);
            f32x2 al2 = (f32x2){al, al};
            uint2 p  = pv[h][i];
            f32x2 f01 = __builtin_amdgcn_cvt_pk_f32_fp8(p.x, false);
            f32x2 f23 = __builtin_amdgcn_cvt_pk_f32_fp8(p.x, true);
            f32x2 f45 = __builtin_amdgcn_cvt_pk_f32_fp8(p.y, false);
            f32x2 f67 = __builtin_amdgcn_cvt_pk_f32_fp8(p.y, true);
            acc2[0] += al2 * f01;
            acc2[1] += al2 * f23;
            acc2[2] += al2 * f45;
            acc2[3] += al2 * f67;
        }
        #pragma unroll
        for (int c = 0; c < 4; ++c) {
            f32x2 v = acc2[c];
            v.x += __shfl_xor(v.x, 16, 64);
            v.y += __shfl_xor(v.y, 16, 64);
            v.x += __shfl_xor(v.x, 32, 64);
            v.y += __shfl_xor(v.y, 32, 64);
            acc2[c] = v;
        }
        if (g < 2) {
            size_t o = (size_t)n * 384 + h * 128 + gl * 8 + g * 4;
            float4 zn;
            if (g == 0) zn = make_float4(acc2[0].x, acc2[0].y, acc2[1].x, acc2[1].y);
            else        zn = make_float4(acc2[2].x, acc2[2].y, acc2[3].x, acc2[3].y);
            float4 r;
            r.x = fmaxf(zc[h].x + zn.x + bb[h].x, 0.f);
            r.y = fmaxf(zc[h].y + zn.y + bb[h].y, 0.f);
            r.z = fmaxf(zc[h].z + zn.z + bb[h].z, 0.f);
            r.w = fmaxf(zc[h].w + zn.w + bb[h].w, 0.f);
            *(float4*)&out[o] = r;
        }
    }
}

// ---------------------------------------------------------------------------
extern "C" void kernel_launch(void* const* d_in, const int* in_sizes, int n_in,
                              void* d_out, int out_size, void* d_ws, size_t ws_size,
                              hipStream_t stream) {
    const float* vertices    = (const float*)d_in[0];
    const int*   nh_indices  = (const int*)d_in[1];
    const int*   int_indices = (const int*)d_in[2];
    const float* nh_edges    = (const float*)d_in[3];
    const float* int_edges   = (const float*)d_in[4];
    // d_in[5] is_int: unused by the reference
    const float* Wvc     = (const float*)d_in[6];
    const float* bv      = (const float*)d_in[7];
    const float* Wvn_int = (const float*)d_in[8];
    const float* Wvn_nh  = (const float*)d_in[9];
    const float* a       = (const float*)d_in[10];
    float* out = (float*)d_out;

    char* ws = (char*)d_ws;
    size_t off = 0;
    unsigned short* Wt = (unsigned short*)(ws + off);
    off += (size_t)WTOT * 2;                  off = (off + 255) & ~(size_t)255;
    unsigned short* wab = (unsigned short*)(ws + off);
    off += (size_t)WACT * 2;                  off = (off + 255) & ~(size_t)255;
    unsigned short* Xb = (unsigned short*)(ws + off);
    off += (size_t)N_V * 128 * 2;             off = (off + 255) & ~(size_t)255;
    uint8_t* Vint = (uint8_t*)(ws + off);
    off += (size_t)H_DIM * N_V * 128;         off = (off + 255) & ~(size_t)255;
    uint8_t* Vnh = (uint8_t*)(ws + off);
    off += (size_t)H_DIM * N_V * 128;         off = (off + 255) & ~(size_t)255;
    float* ec4 = (float*)(ws + off);
    off += (size_t)N_V * 4 * 4;               off = (off + 255) & ~(size_t)255;
    float* ei4 = (float*)(ws + off);
    off += (size_t)N_V * 4 * 4;               off = (off + 255) & ~(size_t)255;
    float* en4 = (float*)(ws + off);
    off += (size_t)N_V * 4 * 4;

    int prep_threads = WTOT + XCH + WACT;
    prep<<<(prep_threads + 255) / 256, 256, 0, stream>>>(
        Wvc, Wvn_int, Wvn_nh, vertices, a, Wt, Xb, wab);

    gemm_kernel<<<NBLK_PAD, 256, 0, stream>>>(
        Xb, Wt, wab, (_Float16*)out, Vint, Vnh, ec4, ei4, en4);

    attn_kernel<<<(N_V + 3) / 4, 256, 0, stream>>>(
        nh_indices, int_indices, nh_edges, int_edges, bv,
        Vint, Vnh, ec4, ei4, en4, out);
}